// Round 5
// baseline (89549.261 us; speedup 1.0000x reference)
//
#include <hip/hip_runtime.h>
#include <stdint.h>

// TLSTM: batch-1 LSTM, T=16384, IN=512, H=1024, OUT=64.
// 256 WGs x 256 threads (1 WG/CU, 1 wave/SIMD). Wave w of WG b owns h-elem
// 4b+w and its 4 gate rows.
//
// KEY FIX vs R1-R4: VGPR_Count was 72 in every round => the 96 floats/lane
// of weights were NEVER register-resident; they re-streamed ~98KB/WG/step
// from L1/L2 on the post-barrier critical path (~1700+ cyc/step, the
// dominant term). amdgpu_waves_per_eu(1,1) raises the allocator's VGPR
// budget to 512 so the asm-pinned weights actually stay in registers.
// (We run exactly 1 wave/EU anyway, so the occupancy cap costs nothing.)
//
// SECOND FIX: no barrier, no LDS. Each lane needs only 16 h-values
// (h[c*256+lane*4 .. +3], c=0..3) = exactly 4 dwordx4 polls; it FMAs them
// straight out of the poll registers. Cross-WG exchange: 1024 self-tagged
// 4B words {tag16|bf16} per parity; tag travels with data => no fences.
// Tag induction at wave granularity: a word can't be overwritten t -> t+2
// until every wave stored tag t+1, which requires it passed poll t.
// X is software-pipelined one step ahead (loaded during step t, used t+1).

typedef unsigned int uint32;
typedef unsigned int u32x4 __attribute__((ext_vector_type(4)));
typedef float        f32x4 __attribute__((ext_vector_type(4)));

#define T_STEPS 16384
#define IN_DIM  512
#define H_DIM   1024
#define NWG     256
#define WGSZ    256

__device__ __forceinline__ float sigf(float x) {
    return 1.0f / (1.0f + __expf(-x));
}
__device__ __forceinline__ float tanh_fast(float x) {
    return 2.0f / (1.0f + __expf(-2.0f * x)) - 1.0f;
}
__device__ __forceinline__ float dot4(f32x4 a, f32x4 b) {
    return a.x * b.x + a.y * b.y + a.z * b.z + a.w * b.w;
}
__device__ __forceinline__ unsigned f32_to_bf16_bits(float f) {
    unsigned u = __float_as_uint(f);
    return (u + 0x7fffu + ((u >> 16) & 1u)) >> 16;
}

__global__ __attribute__((amdgpu_flat_work_group_size(WGSZ, WGSZ),
                          amdgpu_waves_per_eu(1, 1)))
void lstm_seq(const float* __restrict__ X,
              const float* __restrict__ W_ih,
              const float* __restrict__ W_hh,
              const float* __restrict__ b_ih,
              const float* __restrict__ b_hh,
              uint32* __restrict__ hbuf)   // [2][H_DIM] 4B tagged words
{
    const int b    = blockIdx.x;      // 0..255
    const int tid  = threadIdx.x;     // 0..255
    const int w    = tid >> 6;        // wave id 0..3
    const int lane = tid & 63;
    const int elem = 4 * b + w;       // h index this wave produces

    // ---- one-time: weights into registers (then pinned) ----
    // lane covers k = c*256 + lane*4 + {0..3}
    f32x4 wh[4][4];   // [gate][chunk] over H_DIM
    f32x4 wx[4][2];   // [gate][chunk] over IN_DIM
    float bias_g[4];
    #pragma unroll
    for (int g = 0; g < 4; ++g) {
        const int row = g * H_DIM + elem;
        #pragma unroll
        for (int c = 0; c < 4; ++c)
            wh[g][c] = *(const f32x4*)(W_hh + (size_t)row * H_DIM + (c * 256 + lane * 4));
        #pragma unroll
        for (int c = 0; c < 2; ++c)
            wx[g][c] = *(const f32x4*)(W_ih + (size_t)row * IN_DIM + (c * 256 + lane * 4));
        bias_g[g] = b_ih[row] + b_hh[row];
    }
    #pragma unroll
    for (int g = 0; g < 4; ++g) {
        #pragma unroll
        for (int c = 0; c < 4; ++c) asm volatile("" : "+v"(wh[g][c]));
        #pragma unroll
        for (int c = 0; c < 2; ++c) asm volatile("" : "+v"(wx[g][c]));
        asm volatile("" : "+v"(bias_g[g]));
    }

    // x for step 0, preloaded; thereafter pipelined one step ahead
    f32x4 xq0 = *(const f32x4*)(X + lane * 4);
    f32x4 xq1 = *(const f32x4*)(X + 256 + lane * 4);

    float c_state = 0.0f;

    for (int t = 0; t < T_STEPS; ++t) {
        const unsigned want = (unsigned)t;   // 16-bit tag, t < 65536
        const uint32* hp = hbuf + (size_t)(t & 1) * H_DIM + (lane << 2);

        // ---- issue this lane's 4 poll loads (no wait yet) ----
        u32x4 v0, v1, v2, v3;
        asm volatile(
            "global_load_dwordx4 %0, %4, off sc0 sc1\n\t"
            "global_load_dwordx4 %1, %4, off offset:1024 sc0 sc1\n\t"
            "global_load_dwordx4 %2, %4, off offset:2048 sc0 sc1\n\t"
            "global_load_dwordx4 %3, %4, off offset:3072 sc0 sc1"
            : "=v"(v0), "=v"(v1), "=v"(v2), "=v"(v3)
            : "v"(hp) : "memory");

        // ---- x-part dots (xq loaded last step; compiler's waitcnt here
        //      also drains poll round 1 -- harmless, round 1 rarely hits) ----
        float acc0 = dot4(wx[0][0], xq0) + dot4(wx[0][1], xq1);
        float acc1 = dot4(wx[1][0], xq0) + dot4(wx[1][1], xq1);
        float acc2 = dot4(wx[2][0], xq0) + dot4(wx[2][1], xq1);
        float acc3 = dot4(wx[3][0], xq0) + dot4(wx[3][1], xq1);

        // ---- spin until all 16 tags == t ----
        for (;;) {
            asm volatile("s_waitcnt vmcnt(0)"
                         : "+v"(v0), "+v"(v1), "+v"(v2), "+v"(v3) :: "memory");
            const unsigned bad =
                ((v0.x >> 16) ^ want) | ((v0.y >> 16) ^ want) |
                ((v0.z >> 16) ^ want) | ((v0.w >> 16) ^ want) |
                ((v1.x >> 16) ^ want) | ((v1.y >> 16) ^ want) |
                ((v1.z >> 16) ^ want) | ((v1.w >> 16) ^ want) |
                ((v2.x >> 16) ^ want) | ((v2.y >> 16) ^ want) |
                ((v2.z >> 16) ^ want) | ((v2.w >> 16) ^ want) |
                ((v3.x >> 16) ^ want) | ((v3.y >> 16) ^ want) |
                ((v3.z >> 16) ^ want) | ((v3.w >> 16) ^ want);
            if (!bad) break;
            asm volatile(
                "global_load_dwordx4 %0, %4, off sc0 sc1\n\t"
                "global_load_dwordx4 %1, %4, off offset:1024 sc0 sc1\n\t"
                "global_load_dwordx4 %2, %4, off offset:2048 sc0 sc1\n\t"
                "global_load_dwordx4 %3, %4, off offset:3072 sc0 sc1"
                : "+v"(v0), "+v"(v1), "+v"(v2), "+v"(v3)
                : "v"(hp) : "memory");
        }

        // ---- h-part dots straight from poll registers ----
        {
            f32x4 hv;
            hv.x = __uint_as_float(v0.x << 16); hv.y = __uint_as_float(v0.y << 16);
            hv.z = __uint_as_float(v0.z << 16); hv.w = __uint_as_float(v0.w << 16);
            acc0 += dot4(wh[0][0], hv); acc1 += dot4(wh[1][0], hv);
            acc2 += dot4(wh[2][0], hv); acc3 += dot4(wh[3][0], hv);
            hv.x = __uint_as_float(v1.x << 16); hv.y = __uint_as_float(v1.y << 16);
            hv.z = __uint_as_float(v1.z << 16); hv.w = __uint_as_float(v1.w << 16);
            acc0 += dot4(wh[0][1], hv); acc1 += dot4(wh[1][1], hv);
            acc2 += dot4(wh[2][1], hv); acc3 += dot4(wh[3][1], hv);
            hv.x = __uint_as_float(v2.x << 16); hv.y = __uint_as_float(v2.y << 16);
            hv.z = __uint_as_float(v2.z << 16); hv.w = __uint_as_float(v2.w << 16);
            acc0 += dot4(wh[0][2], hv); acc1 += dot4(wh[1][2], hv);
            acc2 += dot4(wh[2][2], hv); acc3 += dot4(wh[3][2], hv);
            hv.x = __uint_as_float(v3.x << 16); hv.y = __uint_as_float(v3.y << 16);
            hv.z = __uint_as_float(v3.z << 16); hv.w = __uint_as_float(v3.w << 16);
            acc0 += dot4(wh[0][3], hv); acc1 += dot4(wh[1][3], hv);
            acc2 += dot4(wh[2][3], hv); acc3 += dot4(wh[3][3], hv);
        }

        // ---- wave butterfly reduce ----
        #pragma unroll
        for (int off = 32; off >= 1; off >>= 1) {
            acc0 += __shfl_xor(acc0, off);
            acc1 += __shfl_xor(acc1, off);
            acc2 += __shfl_xor(acc2, off);
            acc3 += __shfl_xor(acc3, off);
        }

        // ---- combine (uniform across lanes) ----
        const float ii = sigf(acc0 + bias_g[0]);
        const float ff = sigf(acc1 + bias_g[1]);
        const float gg = tanh_fast(acc2 + bias_g[2]);
        const float oo = sigf(acc3 + bias_g[3]);
        const float cn = ff * c_state + ii * gg;
        c_state = cn;
        const float hn = oo * tanh_fast(cn);

        // ---- immediate per-wave store: {tag16=t+1 | bf16(hn)} ----
        if (lane == 0) {
            const uint32 word = (((unsigned)(t + 1)) << 16) | f32_to_bf16_bits(hn);
            __hip_atomic_store(hbuf + (size_t)((t + 1) & 1) * H_DIM + elem,
                               word, __ATOMIC_RELAXED, __HIP_MEMORY_SCOPE_AGENT);
        }

        // ---- prefetch x for step t+1 (full step of slack to complete) ----
        const float* xn = X + (size_t)((t + 1 < T_STEPS) ? t + 1 : t) * IN_DIM;
        xq0 = *(const f32x4*)(xn + lane * 4);
        xq1 = *(const f32x4*)(xn + 256 + lane * 4);
    }
}

__global__ __launch_bounds__(256, 1) void lstm_head(
    const uint32* __restrict__ hbuf,
    const float* __restrict__ W_lin,
    const float* __restrict__ b_lin,
    float* __restrict__ out)
{
    const int tid  = threadIdx.x;
    const int o    = tid >> 2;       // output index, 4 threads per output
    const int part = tid & 3;
    // final h (tag T) is in parity (T&1)=0. Coherent loads: these words were
    // written sc1 (L2-bypass), so plain cached reads could see a stale L2 line.
    const uint32* src = hbuf + (size_t)(T_STEPS & 1) * H_DIM;

    float sum = 0.f;
    const int k0 = part * 256;
    for (int k = k0; k < k0 + 256; ++k) {
        const uint32 v = __hip_atomic_load(src + k, __ATOMIC_RELAXED,
                                           __HIP_MEMORY_SCOPE_AGENT);
        sum += W_lin[(size_t)o * H_DIM + k] * __uint_as_float(v << 16);
    }
    sum += __shfl_xor(sum, 1);
    sum += __shfl_xor(sum, 2);
    if (part == 0)
        out[o] = 1.0f / (1.0f + __expf(-(sum + b_lin[o])));
}

extern "C" void kernel_launch(void* const* d_in, const int* in_sizes, int n_in,
                              void* d_out, int out_size, void* d_ws, size_t ws_size,
                              hipStream_t stream) {
    const float* X     = (const float*)d_in[0];
    // d_in[1] Mask, d_in[2] Delta, d_in[3] dt: unused by the forward pass
    const float* W_ih  = (const float*)d_in[4];
    const float* W_hh  = (const float*)d_in[5];
    const float* b_ih  = (const float*)d_in[6];
    const float* b_hh  = (const float*)d_in[7];
    const float* W_lin = (const float*)d_in[8];
    const float* b_lin = (const float*)d_in[9];
    float* out = (float*)d_out;

    uint32* hbuf = (uint32*)d_ws;   // 2 * 1024 * 4B = 8 KiB used

    // init: both parity buffers = {tag=0, h=0} (all zero bytes)
    hipMemsetAsync(hbuf, 0, 2 * H_DIM * sizeof(uint32), stream);

    lstm_seq<<<NWG, WGSZ, 0, stream>>>(X, W_ih, W_hh, b_ih, b_hh, hbuf);
    lstm_head<<<1, 256, 0, stream>>>(hbuf, W_lin, b_lin, out);
}

// Round 6
// 69114.606 us; speedup vs baseline: 1.2957x; 1.2957x over previous
//
#include <hip/hip_runtime.h>
#include <stdint.h>

// TLSTM: batch-1 LSTM, T=16384, IN=512, H=1024, OUT=64.
// R6 = R1's empirically-best sync structure + registered weights.
//
// Sync (R1, best of 5 measured variants): 256 WGs x 256 thr (1 WG/CU).
// Exchange = 2x1024 u64 words {tag32|fp32} (parity double-buffer). Each
// thread polls 4 distinct words with a done-mask (minimal requesters per
// MALL line; partial retries), stages them to LDS, one barrier, then each
// wave reads all 1024 h from LDS for its dots. Evidence R2-R5: every
// alternative (wider redundant polls, packed words, tight vmcnt(0)
// rounds, no-barrier) increased fabric traffic and duration ~linearly.
//
// Fix vs R1 (the one defect): VGPR_Count=68 meant the 96 weights/lane
// were NEVER resident -- ~98KB/WG restreamed from L2 every step on the
// post-barrier serial path (~1500 cyc/step). amdgpu_waves_per_eu(1,1)
// raises the allocator budget to 512 VGPRs (we run 1 wave/EU anyway);
// empty-asm pins stop rematerialization. R5 proved the mechanism
// (VGPR 132) but buried it under a sync redesign regression.
// Also: x handled as a register pipeline (prefetch at loop end, dots in
// poll-skew window) -- R1 exposed the cold-HBM x load before its spin.

typedef unsigned long long u64;
typedef float f32x4 __attribute__((ext_vector_type(4)));

#define T_STEPS 16384
#define IN_DIM  512
#define H_DIM   1024
#define NWG     256
#define WGSZ    256

__device__ __forceinline__ float sigf(float x) {
    return 1.0f / (1.0f + __expf(-x));
}
__device__ __forceinline__ float tanh_fast(float x) {
    return 2.0f / (1.0f + __expf(-2.0f * x)) - 1.0f;
}
__device__ __forceinline__ float dot4(f32x4 a, f32x4 b) {
    return a.x * b.x + a.y * b.y + a.z * b.z + a.w * b.w;
}

__global__ __attribute__((amdgpu_flat_work_group_size(WGSZ, WGSZ),
                          amdgpu_waves_per_eu(1, 1)))
void lstm_seq(const float* __restrict__ X,
              const float* __restrict__ W_ih,
              const float* __restrict__ W_hh,
              const float* __restrict__ b_ih,
              const float* __restrict__ b_hh,
              u64* __restrict__ hbuf)   // [2][H_DIM] tagged words in d_ws
{
    const int b    = blockIdx.x;      // 0..255
    const int tid  = threadIdx.x;     // 0..255
    const int w    = tid >> 6;        // wave id 0..3
    const int lane = tid & 63;
    const int elem = 4 * b + w;       // h index this wave produces

    __shared__ float h_lds[2][H_DIM];   // 8 KiB

    // ---- one-time: weights into registers, then pinned ----
    // lane covers k = c*256 + lane*4 + {0..3}
    f32x4 wh[4][4];   // [gate][chunk] over H_DIM=1024
    f32x4 wx[4][2];   // [gate][chunk] over IN_DIM=512
    float bias_g[4];
    #pragma unroll
    for (int g = 0; g < 4; ++g) {
        const int row = g * H_DIM + elem;
        #pragma unroll
        for (int c = 0; c < 4; ++c)
            wh[g][c] = *(const f32x4*)(W_hh + (size_t)row * H_DIM + (c * 256 + lane * 4));
        #pragma unroll
        for (int c = 0; c < 2; ++c)
            wx[g][c] = *(const f32x4*)(W_ih + (size_t)row * IN_DIM + (c * 256 + lane * 4));
        bias_g[g] = b_ih[row] + b_hh[row];
    }
    #pragma unroll
    for (int g = 0; g < 4; ++g) {
        #pragma unroll
        for (int c = 0; c < 4; ++c) asm volatile("" : "+v"(wh[g][c]));
        #pragma unroll
        for (int c = 0; c < 2; ++c) asm volatile("" : "+v"(wx[g][c]));
        asm volatile("" : "+v"(bias_g[g]));
    }

    // x register pipeline: xq holds row t's data at the top of iteration t
    f32x4 xq0 = *(const f32x4*)(X + lane * 4);
    f32x4 xq1 = *(const f32x4*)(X + 256 + lane * 4);

    float c_state = 0.0f;

    for (int t = 0; t < T_STEPS; ++t) {
        const int p = t & 1;
        const unsigned want = (unsigned)t;

        // ---- poll h[t]: 4 tagged words/thread, done-mask partial retry
        //      (R1 mechanism -- minimal per-line requesters, self-paced) ----
        {
            const u64* src = hbuf + (size_t)p * H_DIM + tid * 4;
            unsigned done = 0;
            while (done != 0xFu) {
                #pragma unroll
                for (int m = 0; m < 4; ++m) {
                    if (!((done >> m) & 1u)) {
                        u64 v = __hip_atomic_load(src + m, __ATOMIC_RELAXED,
                                                  __HIP_MEMORY_SCOPE_AGENT);
                        if ((unsigned)(v >> 32) == want) {
                            h_lds[p][tid * 4 + m] =
                                __uint_as_float((unsigned)(v & 0xffffffffu));
                            done |= (1u << m);
                        }
                    }
                }
            }
        }

        // ---- x-part dots from registers (hidden in inter-thread poll skew) ----
        float acc0 = dot4(wx[0][0], xq0) + dot4(wx[0][1], xq1);
        float acc1 = dot4(wx[1][0], xq0) + dot4(wx[1][1], xq1);
        float acc2 = dot4(wx[2][0], xq0) + dot4(wx[2][1], xq1);
        float acc3 = dot4(wx[3][0], xq0) + dot4(wx[3][1], xq1);

        __syncthreads();   // single barrier per step: h_lds[p] fully staged

        // ---- h-part dots (weights in VGPRs, h from LDS) ----
        const f32x4* h4 = (const f32x4*)(&h_lds[p][0]);
        #pragma unroll
        for (int c = 0; c < 4; ++c) {
            const f32x4 hv = h4[c * 64 + lane];
            acc0 += dot4(wh[0][c], hv);
            acc1 += dot4(wh[1][c], hv);
            acc2 += dot4(wh[2][c], hv);
            acc3 += dot4(wh[3][c], hv);
        }

        // ---- full-wave butterfly reduce ----
        #pragma unroll
        for (int off = 32; off >= 1; off >>= 1) {
            acc0 += __shfl_xor(acc0, off);
            acc1 += __shfl_xor(acc1, off);
            acc2 += __shfl_xor(acc2, off);
            acc3 += __shfl_xor(acc3, off);
        }

        // ---- combine (uniform across lanes) ----
        const float ii = sigf(acc0 + bias_g[0]);
        const float ff = sigf(acc1 + bias_g[1]);
        const float gg = tanh_fast(acc2 + bias_g[2]);
        const float oo = sigf(acc3 + bias_g[3]);
        const float cn = ff * c_state + ii * gg;
        c_state = cn;
        const float hn = oo * tanh_fast(cn);

        // ---- per-wave immediate store: {tag32=t+1 | fp32 hn} ----
        if (lane == 0) {
            const u64 word = ((u64)(unsigned)(t + 1) << 32)
                           | (u64)__float_as_uint(hn);
            __hip_atomic_store(hbuf + (size_t)((t + 1) & 1) * H_DIM + elem,
                               word, __ATOMIC_RELAXED, __HIP_MEMORY_SCOPE_AGENT);
        }

        // ---- prefetch x row t+1 (a full sync-latency of slack to land) ----
        const float* xn = X + (size_t)((t + 1 < T_STEPS) ? t + 1 : t) * IN_DIM;
        xq0 = *(const f32x4*)(xn + lane * 4);
        xq1 = *(const f32x4*)(xn + 256 + lane * 4);
        // No second barrier (R1-proven): h_lds[p] is not rewritten until
        // step t+2's poll succeeds, which transitively requires every wave
        // to have finished step t+1 and thus left this step's reads.
    }
}

__global__ __launch_bounds__(256, 1) void lstm_head(
    const u64* __restrict__ hbuf,
    const float* __restrict__ W_lin,
    const float* __restrict__ b_lin,
    float* __restrict__ out)
{
    const int tid  = threadIdx.x;
    const int o    = tid >> 2;       // output index, 4 threads per output
    const int part = tid & 3;
    const u64* src = hbuf + (size_t)(T_STEPS & 1) * H_DIM;  // parity 0: tag T

    float sum = 0.f;
    const int k0 = part * 256;
    for (int k = k0; k < k0 + 256; k += 4) {
        const f32x4 wv = *(const f32x4*)(W_lin + (size_t)o * H_DIM + k);
        sum += wv.x * __uint_as_float((unsigned)src[k + 0])
             + wv.y * __uint_as_float((unsigned)src[k + 1])
             + wv.z * __uint_as_float((unsigned)src[k + 2])
             + wv.w * __uint_as_float((unsigned)src[k + 3]);
    }
    sum += __shfl_xor(sum, 1);
    sum += __shfl_xor(sum, 2);
    if (part == 0)
        out[o] = 1.0f / (1.0f + __expf(-(sum + b_lin[o])));
}

extern "C" void kernel_launch(void* const* d_in, const int* in_sizes, int n_in,
                              void* d_out, int out_size, void* d_ws, size_t ws_size,
                              hipStream_t stream) {
    const float* X     = (const float*)d_in[0];
    // d_in[1] Mask, d_in[2] Delta, d_in[3] dt: unused by the forward pass
    const float* W_ih  = (const float*)d_in[4];
    const float* W_hh  = (const float*)d_in[5];
    const float* b_ih  = (const float*)d_in[6];
    const float* b_hh  = (const float*)d_in[7];
    const float* W_lin = (const float*)d_in[8];
    const float* b_lin = (const float*)d_in[9];
    float* out = (float*)d_out;

    u64* hbuf = (u64*)d_ws;   // 2 * 1024 * 8B = 16 KiB used

    // init: both parity buffers = {tag=0, h=0.0f} (all zero bytes)
    hipMemsetAsync(hbuf, 0, 2 * H_DIM * sizeof(u64), stream);

    lstm_seq<<<NWG, WGSZ, 0, stream>>>(X, W_ih, W_hh, b_ih, b_hh, hbuf);
    lstm_head<<<1, 256, 0, stream>>>(hbuf, W_lin, b_lin, out);
}